// Round 15
// baseline (752.004 us; speedup 1.0000x reference)
//
#include <hip/hip_runtime.h>
#include <float.h>
#include <math.h>

// Problem constants: B=2, N=1024, QDIM=512, HEADS=4, DHEAD=64, HID=64, CDIM=16, INNER=256

// workspace byte offsets
#define WS_PM    0u          // pair_mask as u8, 2 MB
#define WS_VM    2097152u    // valid_mask as u8, 2 KB
#define WS_W1TB  2100224u    // w1 bf16 [e=64][k=32] zero-padded k>=16 (4 KB)
#define WS_W2TB  2104320u    // w2 bf16 [d=64][e=64] (8 KB)
#define WS_OWBT  2112512u    // ow bf16 [h=16 pad][e=64] (2 KB)
#define WS_TT    2116608u    // T_catT bf16 [ch=64][entry=192] (24 KB)
#define WS_Q     4194304u    // q  [b][h][n][d] f32, 2 MB
#define WS_KT    6291456u    // kT [b][h][d][n] f32, 2 MB
#define WS_V     8388608u    // v  [b][h][n][d] f32, 2 MB
#define WS_AO    10485760u   // attn-out [b][n][h][d] f32, 2 MB

typedef __attribute__((ext_vector_type(8))) short short8;
typedef __attribute__((ext_vector_type(4))) float f32x4;

__device__ __forceinline__ unsigned short f2bf(float x) {
    unsigned u = __float_as_uint(x);
    u += 0x7fffu + ((u >> 16) & 1u);   // RNE
    return (unsigned short)(u >> 16);
}
__device__ __forceinline__ unsigned cvt_pk_bf16(float lo, float hi) {
    unsigned r;
    asm("v_cvt_pk_bf16_f32 %0, %1, %2" : "=v"(r) : "v"(lo), "v"(hi));
    return r;
}
// tanh-form gelu via hw exp: g = x * sigmoid(1.5957691x + 0.0713548x^3)
__device__ __forceinline__ float gelu_fast(float x) {
    float x2 = x * x;
    float u = x * fmaf(0.0713548135f, x2, 1.5957691216f);
    float e = __expf(-u);
    return x * __builtin_amdgcn_rcpf(1.0f + e);
}
__device__ __forceinline__ float4 fma4(float s, float4 a, float4 c) {
    c.x = fmaf(s, a.x, c.x); c.y = fmaf(s, a.y, c.y);
    c.z = fmaf(s, a.z, c.z); c.w = fmaf(s, a.w, c.w);
    return c;
}
__device__ __forceinline__ float wave_max(float v) {
#pragma unroll
    for (int m = 1; m < 64; m <<= 1) v = fmaxf(v, __shfl_xor(v, m));
    return v;
}
__device__ __forceinline__ float wave_sum(float v) {
#pragma unroll
    for (int m = 1; m < 64; m <<= 1) v += __shfl_xor(v, m);
    return v;
}

// ---------------- prep: weight reshapes / bf16 casts + concatenated table ----------------
// ttcat[c][e] = T_cat[e][c]; CORRECT entry ranges (R10 bug: edge/sp were swapped in width):
// dist [0,32) dir [32,40) role [40,56) hop [56,72) edge [72,80) sp [80,96)
// same [96,99) deg_j [99,165) ct_j [165,186) pad [186,192)=0
__global__ void prep_kernel(const float* __restrict__ w1, const float* __restrict__ w2,
                            const float* __restrict__ ow,
                            const float* __restrict__ e_dist, const float* __restrict__ e_dir,
                            const float* __restrict__ e_role, const float* __restrict__ e_hop,
                            const float* __restrict__ e_edge, const float* __restrict__ e_sp,
                            const float* __restrict__ e_same, const float* __restrict__ e_deg,
                            const float* __restrict__ e_ct,
                            unsigned short* __restrict__ w1tb,
                            unsigned short* __restrict__ w2tb,
                            unsigned short* __restrict__ owbt,
                            unsigned short* __restrict__ ttcat) {
    int t = threadIdx.x;
    for (int i = t; i < 2048; i += 256) {         // w1tb[e][k], k<16 real else 0
        int e = i >> 5, c = i & 31;
        float v = (c < 16) ? w1[c * 64 + e] : 0.f;
        w1tb[i] = f2bf(v);
    }
    for (int i = t; i < 4096; i += 256) {         // w2tb[d][e]
        int d = i >> 6, e = i & 63;
        w2tb[i] = f2bf(w2[e * 64 + d]);
    }
    for (int i = t; i < 1024; i += 256) {         // owbt[h(16 pad)][e]
        int h = i >> 6, e = i & 63;
        owbt[i] = (h < 4) ? f2bf(ow[e * 4 + h]) : (unsigned short)0;
    }
    for (int i = t; i < 64 * 192; i += 256) {
        int c = i / 192, e = i - (i / 192) * 192;
        float v = 0.f;
        if (e < 32)       v = e_dist[e * 64 + c];
        else if (e < 40)  v = e_dir[(e - 32) * 64 + c];
        else if (e < 56)  v = e_role[(e - 40) * 64 + c];
        else if (e < 72)  v = e_hop[(e - 56) * 64 + c];
        else if (e < 80)  v = e_edge[(e - 72) * 64 + c];
        else if (e < 96)  v = e_sp[(e - 80) * 64 + c];
        else if (e < 99)  v = e_same[(e - 96) * 64 + c];
        else if (e < 165) v = e_deg[(e - 99) * 64 + c];
        else if (e < 186) v = e_ct[(e - 165) * 64 + c];
        ttcat[i] = f2bf(v);
    }
}

// ---------------- masks: dtype-detect + convert to u8 ----------------
__global__ __launch_bounds__(256) void mask_kernel(const void* __restrict__ pm_raw,
                                                   const void* __restrict__ vm_raw,
                                                   unsigned char* __restrict__ pm8,
                                                   unsigned char* __restrict__ vm8) {
    __shared__ int sflag;
    int t = threadIdx.x;
    if (t == 0) sflag = 0;
    __syncthreads();
    const unsigned* p32 = (const unsigned*)pm_raw;
    unsigned acc = 0;
    for (int k = t; k < 1024; k += 256) acc |= (p32[k] & ~1u);
    if (acc) sflag = 1;
    __syncthreads();
    bool u8 = (sflag != 0);
    size_t base = (size_t)blockIdx.x * 1024;
    const unsigned char* p8 = (const unsigned char*)pm_raw;
    const int* pi = (const int*)pm_raw;
    for (int k = t; k < 1024; k += 256) {
        size_t idx = base + (size_t)k;
        pm8[idx] = u8 ? (unsigned char)(p8[idx] != 0) : (unsigned char)(pi[idx] != 0);
    }
    if (blockIdx.x == 0) {
        const unsigned char* v8 = (const unsigned char*)vm_raw;
        const int* vi = (const int*)vm_raw;
        for (int k = t; k < 2048; k += 256)
            vm8[k] = u8 ? (unsigned char)(v8[k] != 0) : (unsigned char)(vi[k] != 0);
    }
}

// ---------------- QKV projection ----------------
__global__ __launch_bounds__(256) void qkv_kernel(const float* __restrict__ x,
        const float* __restrict__ Wq, const float* __restrict__ Wk, const float* __restrict__ Wv,
        float* __restrict__ q, float* __restrict__ kt, float* __restrict__ v) {
    __shared__ float As[32][68];
    __shared__ float Bs[32][68];
    int tid = threadIdx.x;
    int bx = blockIdx.x, by = blockIdx.y;
    int mat = bx >> 2;
    const float* __restrict__ W = (mat == 0) ? Wq : ((mat == 1) ? Wk : Wv);
    int col0 = (bx & 3) * 64;
    int row0 = by * 64;
    int tx = tid & 15, ty = tid >> 4;
    int lm = tid >> 3, lk = (tid & 7) * 4;
    int bn = (tid & 15) * 4, bk = tid >> 4;
    float4 acc0 = {0,0,0,0}, acc1 = acc0, acc2 = acc0, acc3 = acc0;
    for (int k0 = 0; k0 < 512; k0 += 32) {
        float4 a0 = *(const float4*)&x[(size_t)(row0 + lm) * 512 + k0 + lk];
        float4 a1 = *(const float4*)&x[(size_t)(row0 + lm + 32) * 512 + k0 + lk];
        float4 b0 = *(const float4*)&W[(size_t)(k0 + bk) * 256 + col0 + bn];
        float4 b1 = *(const float4*)&W[(size_t)(k0 + bk + 16) * 256 + col0 + bn];
        __syncthreads();
        As[lk + 0][lm] = a0.x; As[lk + 1][lm] = a0.y; As[lk + 2][lm] = a0.z; As[lk + 3][lm] = a0.w;
        As[lk + 0][lm + 32] = a1.x; As[lk + 1][lm + 32] = a1.y; As[lk + 2][lm + 32] = a1.z; As[lk + 3][lm + 32] = a1.w;
        *(float4*)&Bs[bk][bn] = b0;
        *(float4*)&Bs[bk + 16][bn] = b1;
        __syncthreads();
#pragma unroll
        for (int kk = 0; kk < 32; ++kk) {
            float4 av = *(const float4*)&As[kk][ty * 4];
            float4 bv = *(const float4*)&Bs[kk][tx * 4];
            acc0 = fma4(av.x, bv, acc0);
            acc1 = fma4(av.y, bv, acc1);
            acc2 = fma4(av.z, bv, acc2);
            acc3 = fma4(av.w, bv, acc3);
        }
    }
#pragma unroll
    for (int r = 0; r < 4; ++r) {
        float4 a = (r == 0) ? acc0 : ((r == 1) ? acc1 : ((r == 2) ? acc2 : acc3));
        int gr = row0 + ty * 4 + r;
        int b = gr >> 10, n = gr & 1023;
        float vals[4] = {a.x, a.y, a.z, a.w};
#pragma unroll
        for (int c = 0; c < 4; ++c) {
            int cc = col0 + tx * 4 + c;
            int h = cc >> 6, d = cc & 63;
            size_t bh = (size_t)(b * 4 + h);
            float val = vals[c];
            if (mat == 0)      q[(bh * 1024 + n) * 64 + d] = val;
            else if (mat == 1) kt[(bh * 64 + d) * 1024 + n] = val;
            else               v[(bh * 1024 + n) * 64 + d] = val;
        }
    }
}

// ---------------- pair bias v9b: ES via one-hot MFMA (fixed segment map) ----------------
// block = 256 threads (4 waves), 64 pair-rows; wave wu owns rows 16wu..16wu+15 END-TO-END.
// ES[16x64] = A_oh[16x192] @ T_cat[192x64] chained directly into GEMM2's accumulator
// (C-in = C-out); per-(b,i) base (b2+deg_i+ct_i) initializes acc2. A_oh lives in
// wave-private LDS (stride 400 B). All LDS rows wave-private (in-wave lgkmcnt ordering,
// no barriers except bias_lds).
__global__ __launch_bounds__(256, 4) void pair_kernel(
        const float* __restrict__ cf,
        const int* __restrict__ i_dist, const int* __restrict__ i_dir,
        const int* __restrict__ i_role, const int* __restrict__ i_hop,
        const int* __restrict__ i_edge, const int* __restrict__ i_sp,
        const int* __restrict__ i_same,
        const int* __restrict__ deg_ids, const int* __restrict__ ct_ids,
        const float* __restrict__ e_deg, const float* __restrict__ e_ct,
        const float* __restrict__ b2,
        const unsigned short* __restrict__ w1tb, const unsigned short* __restrict__ w2tb,
        const unsigned short* __restrict__ owbt, const unsigned short* __restrict__ ttcat,
        const float* __restrict__ b1,
        const float* __restrict__ lng, const float* __restrict__ lnb,
        const float* __restrict__ outb,
        const unsigned char* __restrict__ pm,
        float* __restrict__ bias_out) {
    __shared__ alignas(16) char aoh[4 * 6400];          // A_oh one-hot bf16, per-wave 16 rows x 400 B
    __shared__ alignas(16) unsigned short h1b[64 * 64]; // h1 / gelu_ln bf16, XOR-swizzled, wave-private rows
    __shared__ float prm[192];                          // b1 | lng | lnb (redundantly staged)
    __shared__ float bias_lds[576];                     // bias[64][9]
    __shared__ unsigned long long sptr[9];              // per-table base-adjusted pointers
    __shared__ int soff[9];                             // per-table entry offsets

    int tid = threadIdx.x;
    int wu = __builtin_amdgcn_readfirstlane(tid >> 6);
    int lane = tid & 63;
    int m = lane & 15, g = lane >> 4;
    size_t row0 = (size_t)blockIdx.x * 64;
    int b  = (int)(row0 >> 20);
    int i  = (int)((row0 >> 10) & 1023);
    int j0 = (int)(row0 & 1023);
    int r0 = (int)row0;
    char* aw = aoh + wu * 6400;

    // ---- stage params per-wave redundantly (identical values; no barrier) ----
    for (int k = lane; k < 192; k += 64) {
        float v;
        if (k < 64) v = b1[k];
        else if (k < 128) v = lng[k - 64];
        else v = lnb[k - 128];
        prm[k] = v;
    }
    // ---- stage table ptrs/offsets (every wave writes same values) ----
    if (lane < 9) {
        const void* p; int of;
        switch (lane) {
            case 0: p = i_dist; of = 0;   break;
            case 1: p = i_dir;  of = 32;  break;
            case 2: p = i_role; of = 40;  break;
            case 3: p = i_hop;  of = 56;  break;
            case 4: p = i_edge; of = 72;  break;
            case 5: p = i_sp;   of = 80;  break;   // FIXED: was 88 (sp has 16 entries)
            case 6: p = i_same; of = 96;  break;
            case 7: p = deg_ids; of = 99; break;
            default: p = ct_ids; of = 165; break;
        }
        long basei = (lane < 7) ? (long)r0 : (long)(b * 1024 + j0);
        sptr[lane] = (unsigned long long)((const char*)p + basei * 4);
        soff[lane] = of;
    }

    // ---- GEMM1 A-frag straight from global cf (k 16..31 zero) ----
    short8 afrag1;
    {
        if (g < 2) {
            const float4* cp = (const float4*)&cf[((size_t)(r0 + wu * 16 + m)) * 16 + g * 8];
            float4 c0 = cp[0], c1 = cp[1];
            unsigned p0 = cvt_pk_bf16(c0.x, c0.y), p1 = cvt_pk_bf16(c0.z, c0.w);
            unsigned p2 = cvt_pk_bf16(c1.x, c1.y), p3 = cvt_pk_bf16(c1.z, c1.w);
            int4 tmp = { (int)p0, (int)p1, (int)p2, (int)p3 };
            afrag1 = *(short8*)&tmp;
        } else {
            short8 z = {0,0,0,0,0,0,0,0};
            afrag1 = z;
        }
    }

    // ---- base-init acc2 with b2 + deg_emb[deg_i] + ct_emb[ct_i] (row-invariant) ----
    f32x4 acc2[4];
    {
        int di = deg_ids[b * 1024 + i];
        int ci = ct_ids[b * 1024 + i];
#pragma unroll
        for (int t = 0; t < 4; ++t) {
            int c = t * 16 + m;
            float bv = b2[c] + e_deg[di * 64 + c] + e_ct[ci * 64 + c];
            f32x4 ini = {bv, bv, bv, bv};
            acc2[t] = ini;
        }
    }

    // ---- clear A_oh (wave-private 6400 B) ----
    {
        uint4 z = {0u, 0u, 0u, 0u};
#pragma unroll
        for (int rr = 0; rr < 6; ++rr) *(uint4*)(aw + rr * 1024 + lane * 16) = z;
        if (lane < 16) *(uint4*)(aw + 6144 + lane * 16) = z;
    }
    // ---- scatter: 9 one-hot bf16 1.0 per row; lane (m,g) handles table t=4*ps+g, row m ----
#pragma unroll
    for (int ps = 0; ps < 3; ++ps) {
        int t = ps * 4 + g;
        if (t < 9) {
            unsigned long long p = sptr[t];
            int of = soff[t];
            int idx = *(const int*)((const char*)p + (size_t)(wu * 16 + m) * 4);
            *(unsigned short*)(aw + m * 400 + (of + idx) * 2) = (unsigned short)0x3F80;
        }
    }

    // ---- GEMM1: h1_pre[16x64] = cf[16x32] @ w1[32x64] ----
    f32x4 acc1[4] = {{0,0,0,0},{0,0,0,0},{0,0,0,0},{0,0,0,0}};
#pragma unroll
    for (int t = 0; t < 4; ++t) {
        short8 bfrag = *(const short8*)&w1tb[(t * 16 + m) * 32 + g * 8];
        acc1[t] = __builtin_amdgcn_mfma_f32_16x16x32_bf16(afrag1, bfrag, acc1[t], 0, 0, 0);
    }
    // epilogue 1: +b1, gelu, cvt_pk -> h1b (swizzle ^((row&7)<<4); 128 B rows, bijective)
#pragma unroll
    for (int tp = 0; tp < 2; ++tp) {
#pragma unroll
        for (int r = 0; r < 4; ++r) {
            int rw = wu * 16 + g * 4 + r;
            int c0 = tp * 32 + m, c1 = c0 + 16;
            float g0 = gelu_fast(acc1[tp * 2][r] + prm[c0]);
            float g1 = gelu_fast(acc1[tp * 2 + 1][r] + prm[c1]);
            unsigned pk = cvt_pk_bf16(g0, g1);
            int swz = (rw & 7) << 4;
            *(unsigned short*)((char*)h1b + ((rw * 128 + c0 * 2) ^ swz)) = (unsigned short)pk;
            *(unsigned short*)((char*)h1b + ((rw * 128 + c1 * 2) ^ swz)) = (unsigned short)(pk >> 16);
        }
    }

    // ---- ES-MFMA: acc2 += A_oh[16x192] @ T_cat[192x64] (6 K-steps x 4 ch-tiles) ----
#pragma unroll
    for (int ks = 0; ks < 6; ++ks) {
        short8 ae = *(const short8*)(aw + m * 400 + ks * 64 + g * 16);
#pragma unroll
        for (int t = 0; t < 4; ++t) {
            short8 be = *(const short8*)&ttcat[(size_t)(t * 16 + m) * 192 + ks * 32 + g * 8];
            acc2[t] = __builtin_amdgcn_mfma_f32_16x16x32_bf16(ae, be, acc2[t], 0, 0, 0);
        }
    }

    // ---- GEMM2: acc2 += h1[16x64] @ w2[64x64] (chained accumulator) ----
#pragma unroll
    for (int ks = 0; ks < 2; ++ks) {
        int rowl = wu * 16 + m;
        int byte = (rowl * 128 + ks * 64 + g * 16) ^ ((m & 7) << 4);
        short8 afrag = *(const short8*)((const char*)h1b + byte);
#pragma unroll
        for (int t = 0; t < 4; ++t) {
            short8 bfrag = *(const short8*)&w2tb[(t * 16 + m) * 64 + ks * 32 + g * 8];
            acc2[t] = __builtin_amdgcn_mfma_f32_16x16x32_bf16(afrag, bfrag, acc2[t], 0, 0, 0);
        }
    }

    // ---- epilogue 2a: LN stats straight from acc2 (ES already inside) ----
    float s[4] = {0,0,0,0}, s2[4] = {0,0,0,0};
#pragma unroll
    for (int t = 0; t < 4; ++t) {
#pragma unroll
        for (int r = 0; r < 4; ++r) {
            float v = acc2[t][r];
            s[r] += v; s2[r] = fmaf(v, v, s2[r]);
        }
    }
#pragma unroll
    for (int o = 1; o < 16; o <<= 1) {
#pragma unroll
        for (int r = 0; r < 4; ++r) {
            s[r]  += __shfl_xor(s[r], o);
            s2[r] += __shfl_xor(s2[r], o);
        }
    }
    float mu[4], rs[4];
#pragma unroll
    for (int r = 0; r < 4; ++r) {
        mu[r] = s[r] * 0.015625f;
        float var = fmaxf(s2[r] * 0.015625f - mu[r] * mu[r], 0.f);
        rs[r] = rsqrtf(var + 1e-5f);
    }
    // ---- epilogue 2b: gelu(LN) -> cvt_pk bf16 into h1b (wave-private WAR; bijective swz) ----
#pragma unroll
    for (int tp = 0; tp < 2; ++tp) {
#pragma unroll
        for (int r = 0; r < 4; ++r) {
            int rowl = wu * 16 + g * 4 + r;
            int c0 = tp * 32 + m, c1 = c0 + 16;
            float l0 = fmaf((acc2[tp * 2][r] - mu[r]) * rs[r], prm[64 + c0], prm[128 + c0]);
            float l1 = fmaf((acc2[tp * 2 + 1][r] - mu[r]) * rs[r], prm[64 + c1], prm[128 + c1]);
            unsigned pk = cvt_pk_bf16(gelu_fast(l0), gelu_fast(l1));
            int swz = (rowl & 7) << 4;
            *(unsigned short*)((char*)h1b + ((rowl * 128 + c0 * 2) ^ swz)) = (unsigned short)pk;
            *(unsigned short*)((char*)h1b + ((rowl * 128 + c1 * 2) ^ swz)) = (unsigned short)(pk >> 16);
        }
    }
    // ---- GEMM3: bias[16 rows x 16 cols(4 used)] = gelu_ln[16x64] @ ow_pad[64x16] ----
    f32x4 accH = {0,0,0,0};
#pragma unroll
    for (int ks = 0; ks < 2; ++ks) {
        int rowl = wu * 16 + m;
        int byte = (rowl * 128 + ks * 64 + g * 16) ^ ((m & 7) << 4);
        short8 afrag = *(const short8*)((const char*)h1b + byte);
        short8 bfrag = *(const short8*)&owbt[m * 64 + ks * 32 + g * 8];
        accH = __builtin_amdgcn_mfma_f32_16x16x32_bf16(afrag, bfrag, accH, 0, 0, 0);
    }
    // C layout: col = m (head), row = g*4 + r  [m89]; bias_lds rows wave-private
    if (m < 4) {
        float ob = outb[m];
#pragma unroll
        for (int r = 0; r < 4; ++r) {
            int rowl = wu * 16 + g * 4 + r;
            bias_lds[rowl * 9 + m] = accH[r] + ob;
        }
    }
    __syncthreads();   // the ONLY block barrier
    // ---- final: wave wu writes head h=wu, 256 B contiguous full-mask ----
    {
        float pmv = pm[r0 + lane] ? 1.f : 0.f;
        size_t ob = (size_t)(b * 4 + wu) * 1048576u + (size_t)i * 1024u + (size_t)(j0 + lane);
        bias_out[ob] = bias_lds[lane * 9 + wu] * pmv;
    }
}

// ---------------- attention ----------------
__global__ __launch_bounds__(256) void attn_kernel(
        const float* __restrict__ q, const float* __restrict__ kt, const float* __restrict__ v,
        const unsigned char* __restrict__ pm, const unsigned char* __restrict__ vm,
        const float* __restrict__ bias, float* __restrict__ attn, float* __restrict__ ao) {
    __shared__ float pbuf[4][1024];
    int tid = threadIdx.x;
    int w = tid >> 6, lane = tid & 63;
    int blk = blockIdx.x;
    int it = blk & 63;
    int bh = blk >> 6;
    int b = bh >> 2, h = bh & 3;
    int i0 = __builtin_amdgcn_readfirstlane(it * 16 + w * 4);
    const float* __restrict__ qr = q + ((size_t)bh * 1024 + i0) * 64;
    const float4* __restrict__ kt4 = (const float4*)kt;
    const float4* __restrict__ v4 = (const float4*)v;
    const float4* __restrict__ bias4 = (const float4*)bias;
    float4* __restrict__ attn4 = (float4*)attn;
    float4* __restrict__ ao4 = (float4*)ao;

    float4 lg[4][4];
#pragma unroll
    for (int jt = 0; jt < 4; ++jt) {
        float4 a0 = {0,0,0,0}, a1 = a0, a2 = a0, a3 = a0;
#pragma unroll 4
        for (int d = 0; d < 64; ++d) {
            float4 kv = kt4[((size_t)bh * 64 + d) * 256 + jt * 64 + lane];
            a0 = fma4(qr[d], kv, a0);
            a1 = fma4(qr[64 + d], kv, a1);
            a2 = fma4(qr[128 + d], kv, a2);
            a3 = fma4(qr[192 + d], kv, a3);
        }
#pragma unroll
        for (int rr = 0; rr < 4; ++rr) {
            float4 acc = (rr == 0) ? a0 : ((rr == 1) ? a1 : ((rr == 2) ? a2 : a3));
            float4 bv = bias4[((size_t)bh * 1024 + i0 + rr) * 256 + jt * 64 + lane];
            float4 l;
            l.x = fmaf(acc.x, 0.125f, bv.x);
            l.y = fmaf(acc.y, 0.125f, bv.y);
            l.z = fmaf(acc.z, 0.125f, bv.z);
            l.w = fmaf(acc.w, 0.125f, bv.w);
            lg[rr][jt] = l;
        }
    }
#pragma unroll
    for (int rr = 0; rr < 4; ++rr) {
        int i = i0 + rr;
        bool vld = vm[b * 1024 + i] != 0;
        float4 ev[4];
        float pmax = -FLT_MAX;
#pragma unroll
        for (int jt = 0; jt < 4; ++jt) {
            uchar4 m4 = *(const uchar4*)&pm[((size_t)b * 1024 + i) * 1024 + jt * 256 + lane * 4];
            int jb = jt * 256 + lane * 4;
            float4 l = lg[rr][jt];
            l.x = (m4.x || (!vld && (jb + 0) == i)) ? l.x : -FLT_MAX;
            l.y = (m4.y || (!vld && (jb + 1) == i)) ? l.y : -FLT_MAX;
            l.z = (m4.z || (!vld && (jb + 2) == i)) ? l.z : -FLT_MAX;
            l.w = (m4.w || (!vld && (jb + 3) == i)) ? l.w : -FLT_MAX;
            lg[rr][jt] = l;
            pmax = fmaxf(pmax, fmaxf(fmaxf(l.x, l.y), fmaxf(l.z, l.w)));
        }
        pmax = wave_max(pmax);
        float s1sum = 0.f;
#pragma unroll
        for (int jt = 0; jt < 4; ++jt) {
            float4 l = lg[rr][jt];
            float4 e;
            e.x = __expf(l.x - pmax); e.y = __expf(l.y - pmax);
            e.z = __expf(l.z - pmax); e.w = __expf(l.w - pmax);
            ev[jt] = e;
            s1sum += (e.x + e.y) + (e.z + e.w);
        }
        s1sum = wave_sum(s1sum);
        float inv1 = 1.f / s1sum;
        float s2sum = 0.f;
#pragma unroll
        for (int jt = 0; jt < 4; ++jt) {
            uchar4 m4 = *(const uchar4*)&pm[((size_t)b * 1024 + i) * 1024 + jt * 256 + lane * 4];
            float4 e = ev[jt];
            e.x = m4.x ? e.x * inv1 : 0.f;
            e.y = m4.y ? e.y * inv1 : 0.f;
            e.z = m4.z ? e.z * inv1 : 0.f;
            e.w = m4.w ? e.w * inv1 : 0.f;
            ev[jt] = e;
            s2sum += (e.x + e.y) + (e.z + e.w);
        }
        s2sum = wave_sum(s2sum);
        float inv2 = 1.f / fmaxf(s2sum, 1e-6f);
#pragma unroll
        for (int jt = 0; jt < 4; ++jt) {
            float4 e = ev[jt];
            e.x *= inv2; e.y *= inv2; e.z *= inv2; e.w *= inv2;
            attn4[((size_t)bh * 1024 + i) * 256 + jt * 64 + lane] = e;
            *(float4*)&pbuf[w][jt * 256 + lane * 4] = e;
        }
        __syncthreads();
        int dq = lane & 15, grp = lane >> 4;
        float4 o = {0,0,0,0};
#pragma unroll 4
        for (int t = 0; t < 64; ++t) {
            int jj = grp * 4 + t * 16;
            float4 p4 = *(const float4*)&pbuf[w][jj];
            float4 v0 = v4[((size_t)bh * 1024 + jj + 0) * 16 + dq];
            float4 v1 = v4[((size_t)bh * 1024 + jj + 1) * 16 + dq];
            float4 v2 = v4[((size_t)bh * 1024 + jj + 2) * 16 + dq];
            float4 v3 = v4[((size_t)bh * 1024 + jj + 3) * 16 + dq];
            o = fma4(p4.x, v0, o); o = fma4(p4.y, v1, o);
            o = fma4(p4.z, v2, o); o = fma4(p4.w, v3, o);
        }
        o.x += __shfl_xor(o.x, 16); o.y += __shfl_xor(o.y, 16);
        o.z += __shfl_xor(o.z, 16); o.w += __shfl_xor(o.w, 16);
        o.x += __shfl_xor(o.x, 32); o.y += __shfl_xor(o.y, 32);
        o.z += __shfl_xor(o.z, 32); o.w += __shfl_xor(o.w, 32);
        if (grp == 0) ao4[((size_t)(b * 1024 + i) * 4 + h) * 16 + dq] = o;
        __syncthreads();
    }
}

// ---------------- output projection ----------------
__global__ __launch_bounds__(256) void outproj_kernel(
        const float* __restrict__ ao, const float* __restrict__ Wo,
        const float* __restrict__ bo, float* __restrict__ out) {
    __shared__ float As[32][68];
    __shared__ float Bs[32][68];
    int tid = threadIdx.x;
    int bx = blockIdx.x, by = blockIdx.y;
    int col0 = bx * 64, row0 = by * 64;
    int tx = tid & 15, ty = tid >> 4;
    int lm = tid >> 3, lk = (tid & 7) * 4;
    int bn = (tid & 15) * 4, bk = tid >> 4;
    float4 acc0 = {0,0,0,0}, acc1 = acc0, acc2 = acc0, acc3 = acc0;
    for (int k0 = 0; k0 < 256; k0 += 32) {
        float4 a0 = *(const float4*)&ao[(size_t)(row0 + lm) * 256 + k0 + lk];
        float4 a1 = *(const float4*)&ao[(size_t)(row0 + lm + 32) * 256 + k0 + lk];
        float4 b0 = *(const float4*)&Wo[(size_t)(k0 + bk) * 512 + col0 + bn];
        float4 b1 = *(const float4*)&Wo[(size_t)(k0 + bk + 16) * 512 + col0 + bn];
        __syncthreads();
        As[lk + 0][lm] = a0.x; As[lk + 1][lm] = a0.y; As[lk + 2][lm] = a0.z; As[lk + 3][lm] = a0.w;
        As[lk + 0][lm + 32] = a1.x; As[lk + 1][lm + 32] = a1.y; As[lk + 2][lm + 32] = a1.z; As[lk + 3][lm + 32] = a1.w;
        *(float4*)&Bs[bk][bn] = b0;
        *(float4*)&Bs[bk + 16][bn] = b1;
        __syncthreads();
#pragma unroll
        for (int kk = 0; kk < 32; ++kk) {
            float4 av = *(const float4*)&As[kk][ty * 4];
            float4 bv = *(const float4*)&Bs[kk][tx * 4];
            acc0 = fma4(av.x, bv, acc0);
            acc1 = fma4(av.y, bv, acc1);
            acc2 = fma4(av.z, bv, acc2);
            acc3 = fma4(av.w, bv, acc3);
        }
    }
#pragma unroll
    for (int r = 0; r < 4; ++r) {
        float4 a = (r == 0) ? acc0 : ((r == 1) ? acc1 : ((r == 2) ? acc2 : acc3));
        int gr = row0 + ty * 4 + r;
        float vals[4] = {a.x, a.y, a.z, a.w};
#pragma unroll
        for (int c = 0; c < 4; ++c) {
            int gc = col0 + tx * 4 + c;
            out[(size_t)gr * 512 + gc] = vals[c] + bo[gc];
        }
    }
}

extern "C" void kernel_launch(void* const* d_in, const int* in_sizes, int n_in,
                              void* d_out, int out_size, void* d_ws, size_t ws_size,
                              hipStream_t stream) {
    (void)in_sizes; (void)n_in; (void)out_size; (void)ws_size;
    const float* x    = (const float*)d_in[0];
    const void*  pmr  = d_in[1];
    const void*  vmr  = d_in[2];
    const float* cf   = (const float*)d_in[3];
    const int* dist_b = (const int*)d_in[4];
    const int* dir_b  = (const int*)d_in[5];
    const int* role_b = (const int*)d_in[6];
    const int* hop_b  = (const int*)d_in[7];
    const int* edge_b = (const int*)d_in[8];
    const int* sp_b   = (const int*)d_in[9];
    const int* same_b = (const int*)d_in[10];
    const int* deg_ids = (const int*)d_in[11];
    const int* ct_ids  = (const int*)d_in[12];
    const float* Wq = (const float*)d_in[13];
    const float* Wk = (const float*)d_in[14];
    const float* Wv = (const float*)d_in[15];
    const float* Wo = (const float*)d_in[16];
    const float* bo = (const float*)d_in[17];
    const float* w1 = (const float*)d_in[18];
    const float* b1 = (const float*)d_in[19];
    const float* w2 = (const float*)d_in[20];
    const float* b2 = (const float*)d_in[21];
    const float* e_dist = (const float*)d_in[22];
    const float* e_dir  = (const float*)d_in[23];
    const float* e_role = (const float*)d_in[24];
    const float* e_hop  = (const float*)d_in[25];
    const float* e_edge = (const float*)d_in[26];
    const float* e_sp   = (const float*)d_in[27];
    const float* e_deg  = (const float*)d_in[28];
    const float* e_ct   = (const float*)d_in[29];
    const float* e_same = (const float*)d_in[30];
    const float* lng  = (const float*)d_in[31];
    const float* lnb  = (const float*)d_in[32];
    const float* ow   = (const float*)d_in[33];
    const float* outb = (const float*)d_in[34];

    char* ws = (char*)d_ws;
    unsigned char* pm8 = (unsigned char*)(ws + WS_PM);
    unsigned char* vm8 = (unsigned char*)(ws + WS_VM);
    unsigned short* w1tb = (unsigned short*)(ws + WS_W1TB);
    unsigned short* w2tb = (unsigned short*)(ws + WS_W2TB);
    unsigned short* owbt = (unsigned short*)(ws + WS_OWBT);
    unsigned short* ttcat = (unsigned short*)(ws + WS_TT);
    float* q   = (float*)(ws + WS_Q);
    float* kt  = (float*)(ws + WS_KT);
    float* v   = (float*)(ws + WS_V);
    float* ao  = (float*)(ws + WS_AO);

    float* out  = (float*)d_out;
    float* attn = out + 1048576;     // [2,4,1024,1024]
    float* bias = out + 9437184;     // [2,4,1024,1024]

    hipLaunchKernelGGL(prep_kernel, dim3(1), dim3(256), 0, stream, w1, w2, ow,
                       e_dist, e_dir, e_role, e_hop, e_edge, e_sp, e_same, e_deg, e_ct,
                       w1tb, w2tb, owbt, ttcat);
    hipLaunchKernelGGL(mask_kernel, dim3(2048), dim3(256), 0, stream, pmr, vmr, pm8, vm8);
    hipLaunchKernelGGL(qkv_kernel, dim3(12, 32), dim3(256), 0, stream, x, Wq, Wk, Wv, q, kt, v);
    hipLaunchKernelGGL(pair_kernel, dim3(32768), dim3(256), 0, stream,
                       cf, dist_b, dir_b, role_b, hop_b, edge_b, sp_b, same_b, deg_ids, ct_ids,
                       e_deg, e_ct, b2, w1tb, w2tb, owbt, ttcat,
                       b1, lng, lnb, outb, pm8, bias);
    hipLaunchKernelGGL(attn_kernel, dim3(512), dim3(256), 0, stream,
                       q, kt, v, pm8, vm8, bias, attn, ao);
    hipLaunchKernelGGL(outproj_kernel, dim3(8, 32), dim3(256), 0, stream, ao, Wo, bo, out);
}

// Round 16
// 535.223 us; speedup vs baseline: 1.4050x; 1.4050x over previous
//
#include <hip/hip_runtime.h>
#include <float.h>
#include <math.h>

// Problem constants: B=2, N=1024, QDIM=512, HEADS=4, DHEAD=64, HID=64, CDIM=16, INNER=256

// workspace byte offsets
#define WS_PM    0u          // pair_mask as u8, 2 MB
#define WS_VM    2097152u    // valid_mask as u8, 2 KB
#define WS_W1TB  2100224u    // w1 bf16 [e=64][k=32] zero-padded k>=16 (4 KB)
#define WS_W2TB  2104320u    // w2 bf16 [d=64][e=64] (8 KB)
#define WS_OWBT  2112512u    // ow bf16 [h=16 pad][e=64] (2 KB)
#define WS_Q     4194304u    // q  [b][h][n][d] f32, 2 MB
#define WS_KT    6291456u    // kT [b][h][d][n] f32, 2 MB
#define WS_V     8388608u    // v  [b][h][n][d] f32, 2 MB
#define WS_AO    10485760u   // attn-out [b][n][h][d] f32, 2 MB

typedef __attribute__((ext_vector_type(8))) short short8;
typedef __attribute__((ext_vector_type(4))) float f32x4;

__device__ __forceinline__ unsigned short f2bf(float x) {
    unsigned u = __float_as_uint(x);
    u += 0x7fffu + ((u >> 16) & 1u);   // RNE
    return (unsigned short)(u >> 16);
}
__device__ __forceinline__ unsigned cvt_pk_bf16(float lo, float hi) {
    unsigned r;
    asm("v_cvt_pk_bf16_f32 %0, %1, %2" : "=v"(r) : "v"(lo), "v"(hi));
    return r;
}
// tanh-form gelu via hw exp: g = x * sigmoid(1.5957691x + 0.0713548x^3)
__device__ __forceinline__ float gelu_fast(float x) {
    float x2 = x * x;
    float u = x * fmaf(0.0713548135f, x2, 1.5957691216f);
    float e = __expf(-u);
    return x * __builtin_amdgcn_rcpf(1.0f + e);
}
__device__ __forceinline__ float4 fma4(float s, float4 a, float4 c) {
    c.x = fmaf(s, a.x, c.x); c.y = fmaf(s, a.y, c.y);
    c.z = fmaf(s, a.z, c.z); c.w = fmaf(s, a.w, c.w);
    return c;
}
__device__ __forceinline__ float wave_max(float v) {
#pragma unroll
    for (int m = 1; m < 64; m <<= 1) v = fmaxf(v, __shfl_xor(v, m));
    return v;
}
__device__ __forceinline__ float wave_sum(float v) {
#pragma unroll
    for (int m = 1; m < 64; m <<= 1) v += __shfl_xor(v, m);
    return v;
}
__device__ __forceinline__ float4 ldg4(const float* p, int boff) {
    return *(const float4*)((const char*)p + boff);
}
__device__ __forceinline__ float4 add4(float4 a, float4 b) {
    a.x += b.x; a.y += b.y; a.z += b.z; a.w += b.w;
    return a;
}

// ---------------- prep: small weight reshapes / bf16 casts ----------------
__global__ void prep_kernel(const float* __restrict__ w1, const float* __restrict__ w2,
                            const float* __restrict__ ow,
                            unsigned short* __restrict__ w1tb,
                            unsigned short* __restrict__ w2tb,
                            unsigned short* __restrict__ owbt) {
    int t = threadIdx.x;
    for (int i = t; i < 2048; i += 256) {         // w1tb[e][k], k<16 real else 0
        int e = i >> 5, c = i & 31;
        float v = (c < 16) ? w1[c * 64 + e] : 0.f;
        w1tb[i] = f2bf(v);
    }
    for (int i = t; i < 4096; i += 256) {         // w2tb[d][e]
        int d = i >> 6, e = i & 63;
        w2tb[i] = f2bf(w2[e * 64 + d]);
    }
    for (int i = t; i < 1024; i += 256) {         // owbt[h(16 pad)][e]
        int h = i >> 6, e = i & 63;
        owbt[i] = (h < 4) ? f2bf(ow[e * 4 + h]) : (unsigned short)0;
    }
}

// ---------------- masks: dtype-detect + convert to u8 ----------------
__global__ __launch_bounds__(256) void mask_kernel(const void* __restrict__ pm_raw,
                                                   const void* __restrict__ vm_raw,
                                                   unsigned char* __restrict__ pm8,
                                                   unsigned char* __restrict__ vm8) {
    __shared__ int sflag;
    int t = threadIdx.x;
    if (t == 0) sflag = 0;
    __syncthreads();
    const unsigned* p32 = (const unsigned*)pm_raw;
    unsigned acc = 0;
    for (int k = t; k < 1024; k += 256) acc |= (p32[k] & ~1u);
    if (acc) sflag = 1;
    __syncthreads();
    bool u8 = (sflag != 0);
    size_t base = (size_t)blockIdx.x * 1024;
    const unsigned char* p8 = (const unsigned char*)pm_raw;
    const int* pi = (const int*)pm_raw;
    for (int k = t; k < 1024; k += 256) {
        size_t idx = base + (size_t)k;
        pm8[idx] = u8 ? (unsigned char)(p8[idx] != 0) : (unsigned char)(pi[idx] != 0);
    }
    if (blockIdx.x == 0) {
        const unsigned char* v8 = (const unsigned char*)vm_raw;
        const int* vi = (const int*)vm_raw;
        for (int k = t; k < 2048; k += 256)
            vm8[k] = u8 ? (unsigned char)(v8[k] != 0) : (unsigned char)(vi[k] != 0);
    }
}

// ---------------- QKV projection ----------------
__global__ __launch_bounds__(256) void qkv_kernel(const float* __restrict__ x,
        const float* __restrict__ Wq, const float* __restrict__ Wk, const float* __restrict__ Wv,
        float* __restrict__ q, float* __restrict__ kt, float* __restrict__ v) {
    __shared__ float As[32][68];
    __shared__ float Bs[32][68];
    int tid = threadIdx.x;
    int bx = blockIdx.x, by = blockIdx.y;
    int mat = bx >> 2;
    const float* __restrict__ W = (mat == 0) ? Wq : ((mat == 1) ? Wk : Wv);
    int col0 = (bx & 3) * 64;
    int row0 = by * 64;
    int tx = tid & 15, ty = tid >> 4;
    int lm = tid >> 3, lk = (tid & 7) * 4;
    int bn = (tid & 15) * 4, bk = tid >> 4;
    float4 acc0 = {0,0,0,0}, acc1 = acc0, acc2 = acc0, acc3 = acc0;
    for (int k0 = 0; k0 < 512; k0 += 32) {
        float4 a0 = *(const float4*)&x[(size_t)(row0 + lm) * 512 + k0 + lk];
        float4 a1 = *(const float4*)&x[(size_t)(row0 + lm + 32) * 512 + k0 + lk];
        float4 b0 = *(const float4*)&W[(size_t)(k0 + bk) * 256 + col0 + bn];
        float4 b1 = *(const float4*)&W[(size_t)(k0 + bk + 16) * 256 + col0 + bn];
        __syncthreads();
        As[lk + 0][lm] = a0.x; As[lk + 1][lm] = a0.y; As[lk + 2][lm] = a0.z; As[lk + 3][lm] = a0.w;
        As[lk + 0][lm + 32] = a1.x; As[lk + 1][lm + 32] = a1.y; As[lk + 2][lm + 32] = a1.z; As[lk + 3][lm + 32] = a1.w;
        *(float4*)&Bs[bk][bn] = b0;
        *(float4*)&Bs[bk + 16][bn] = b1;
        __syncthreads();
#pragma unroll
        for (int kk = 0; kk < 32; ++kk) {
            float4 av = *(const float4*)&As[kk][ty * 4];
            float4 bv = *(const float4*)&Bs[kk][tx * 4];
            acc0 = fma4(av.x, bv, acc0);
            acc1 = fma4(av.y, bv, acc1);
            acc2 = fma4(av.z, bv, acc2);
            acc3 = fma4(av.w, bv, acc3);
        }
    }
#pragma unroll
    for (int r = 0; r < 4; ++r) {
        float4 a = (r == 0) ? acc0 : ((r == 1) ? acc1 : ((r == 2) ? acc2 : acc3));
        int gr = row0 + ty * 4 + r;
        int b = gr >> 10, n = gr & 1023;
        float vals[4] = {a.x, a.y, a.z, a.w};
#pragma unroll
        for (int c = 0; c < 4; ++c) {
            int cc = col0 + tx * 4 + c;
            int h = cc >> 6, d = cc & 63;
            size_t bh = (size_t)(b * 4 + h);
            float val = vals[c];
            if (mat == 0)      q[(bh * 1024 + n) * 64 + d] = val;
            else if (mat == 1) kt[(bh * 64 + d) * 1024 + n] = val;
            else               v[(bh * 1024 + n) * 64 + d] = val;
        }
    }
}

// ---------------- pair bias v6 (measured best: 419 us): barrier-minimal ----------------
// block = 256 threads (4 waves), 64 pair-rows; wave wu owns rows 16wu..16wu+15 END-TO-END.
// cfb/h1b/es rows are wave-private => within-wave LDS ordering (lgkmcnt) suffices, NO barriers.
// prm: staged redundantly by every wave (identical dword values -> benign concurrent writes).
// idx: loaded directly from global (16-lane-group-uniform addrs, L1 broadcast).
// ONE barrier total: bias_lds (wave-private write rows) -> cross-wave transposed read.
__global__ __launch_bounds__(256, 4) void pair_kernel(
        const float* __restrict__ cf,
        const int* __restrict__ i_dist, const int* __restrict__ i_dir,
        const int* __restrict__ i_role, const int* __restrict__ i_hop,
        const int* __restrict__ i_edge, const int* __restrict__ i_sp,
        const int* __restrict__ i_same,
        const int* __restrict__ deg_ids, const int* __restrict__ ct_ids,
        const float* __restrict__ e_dist, const float* __restrict__ e_dir,
        const float* __restrict__ e_role, const float* __restrict__ e_hop,
        const float* __restrict__ e_edge, const float* __restrict__ e_sp,
        const float* __restrict__ e_same, const float* __restrict__ e_deg,
        const float* __restrict__ e_ct,
        const float* __restrict__ b1, const float* __restrict__ b2,
        const unsigned short* __restrict__ w1tb, const unsigned short* __restrict__ w2tb,
        const unsigned short* __restrict__ owbt,
        const float* __restrict__ lng, const float* __restrict__ lnb,
        const float* __restrict__ outb,
        const unsigned char* __restrict__ pm,
        float* __restrict__ bias_out) {
    __shared__ alignas(8) unsigned short es[64 * 68];   // embedding sums bf16, unswizzled, wave-private rows
    __shared__ alignas(16) unsigned short h1b[64 * 64]; // h1 / gelu_ln bf16, XOR-swizzled, wave-private rows
    __shared__ alignas(16) unsigned short cfb[64 * 32]; // cf bf16, k zero-padded, wave-private rows
    __shared__ float prm[192];                          // b1 | lng | lnb (redundantly staged)
    __shared__ float bias_lds[576];                     // bias[64][9]

    int tid = threadIdx.x;
    int wu = __builtin_amdgcn_readfirstlane(tid >> 6);
    int lane = tid & 63;
    int m = lane & 15, g = lane >> 4;
    size_t row0 = (size_t)blockIdx.x * 64;
    int b  = (int)(row0 >> 20);
    int i  = (int)((row0 >> 10) & 1023);
    int j0 = (int)(row0 & 1023);
    int r0 = (int)row0;

    // ---- stage params per-wave redundantly (same values; no barrier needed) ----
    for (int k = lane; k < 192; k += 64) {
        float v;
        if (k < 64) v = b1[k];
        else if (k < 128) v = lng[k - 64];
        else v = lnb[k - 128];
        prm[k] = v;
    }
    // ---- stage cf rows (wave-private), bf16, zero-pad k 16..31 ----
    {
        int rl = wu * 16 + (lane >> 2);
        int ch = (lane & 3) * 4;
        float4 c4 = *(const float4*)&cf[((size_t)(r0 + rl)) * 16 + ch];
        ushort4 u;
        u.x = f2bf(c4.x); u.y = f2bf(c4.y); u.z = f2bf(c4.z); u.w = f2bf(c4.w);
        *(ushort4*)&cfb[rl * 32 + ch] = u;
        ushort4 z = {0, 0, 0, 0};
        *(ushort4*)&cfb[rl * 32 + 16 + ch] = z;
    }
    // ---- phase 0: float4 packed gathers, idx direct from global, 4 rows/iter ----
    {
        int di = deg_ids[b * 1024 + i];
        int ci = ct_ids[b * 1024 + i];
        int c = lane & 15;           // channel group 4c..4c+3
        int rsub = lane >> 4;        // 0..3
        int choff = c * 16;          // byte offset within a 64-float table row
        float4 base4 = add4(add4(ldg4(b2, choff), ldg4(e_deg + di * 64, choff)),
                            ldg4(e_ct + ci * 64, choff));
#pragma unroll
        for (int it = 0; it < 4; ++it) {
            int row = wu * 16 + it * 4 + rsub;
            int gr = r0 + row;
            int q0 = i_dist[gr], q1 = i_dir[gr], q2 = i_role[gr], q3 = i_hop[gr],
                q4 = i_edge[gr], q5 = i_sp[gr], q6 = i_same[gr];
            int q7 = deg_ids[b * 1024 + j0 + row];
            int q8 = ct_ids[b * 1024 + j0 + row];
            float4 a = base4;
            a = add4(a, ldg4(e_dist, q0 * 256 + choff));
            a = add4(a, ldg4(e_dir,  q1 * 256 + choff));
            a = add4(a, ldg4(e_role, q2 * 256 + choff));
            a = add4(a, ldg4(e_hop,  q3 * 256 + choff));
            a = add4(a, ldg4(e_edge, q4 * 256 + choff));
            a = add4(a, ldg4(e_sp,   q5 * 256 + choff));
            a = add4(a, ldg4(e_same, q6 * 256 + choff));
            a = add4(a, ldg4(e_deg,  q7 * 256 + choff));
            a = add4(a, ldg4(e_ct,   q8 * 256 + choff));
            uint2 pk;
            pk.x = cvt_pk_bf16(a.x, a.y);
            pk.y = cvt_pk_bf16(a.z, a.w);
            // byte addr = row*136 + c*8 : 8-B aligned, unswizzled, wave-private rows
            *(uint2*)((char*)es + row * 136 + c * 8) = pk;
        }
    }

    // ---- GEMM1: h1_pre[16 x 64] = cf[16 x 32] @ w1[32 x 64] (wave-private A rows) ----
    f32x4 acc1[4] = {{0,0,0,0},{0,0,0,0},{0,0,0,0},{0,0,0,0}};
    {
        short8 afrag = *(const short8*)&cfb[(wu * 16 + m) * 32 + g * 8];
#pragma unroll
        for (int t = 0; t < 4; ++t) {
            short8 bfrag = *(const short8*)&w1tb[(t * 16 + m) * 32 + g * 8];
            acc1[t] = __builtin_amdgcn_mfma_f32_16x16x32_bf16(afrag, bfrag, acc1[t], 0, 0, 0);
        }
    }
    // epilogue 1: +b1, gelu, cvt_pk -> h1b (swizzle ^((row&7)<<4); 128 B rows, bijective)
#pragma unroll
    for (int tp = 0; tp < 2; ++tp) {
#pragma unroll
        for (int r = 0; r < 4; ++r) {
            int rowl = wu * 16 + g * 4 + r;
            int c0 = tp * 32 + m, c1 = c0 + 16;
            float g0 = gelu_fast(acc1[tp * 2][r] + prm[c0]);
            float g1 = gelu_fast(acc1[tp * 2 + 1][r] + prm[c1]);
            unsigned pk = cvt_pk_bf16(g0, g1);
            int swz = (rowl & 7) << 4;
            *(unsigned short*)((char*)h1b + ((rowl * 128 + c0 * 2) ^ swz)) = (unsigned short)pk;
            *(unsigned short*)((char*)h1b + ((rowl * 128 + c1 * 2) ^ swz)) = (unsigned short)(pk >> 16);
        }
    }
    // (no barrier: h1b rows wave-private, within-wave LDS ordering via lgkmcnt)

    // ---- GEMM2: pair[16 x 64] = h1[16 x 64] @ w2[64 x 64] ----
    f32x4 acc2[4] = {{0,0,0,0},{0,0,0,0},{0,0,0,0},{0,0,0,0}};
#pragma unroll
    for (int ks = 0; ks < 2; ++ks) {
        int rowl = wu * 16 + m;
        int byte = (rowl * 128 + ks * 64 + g * 16) ^ ((m & 7) << 4);
        short8 afrag = *(const short8*)((const char*)h1b + byte);
#pragma unroll
        for (int t = 0; t < 4; ++t) {
            short8 bfrag = *(const short8*)&w2tb[(t * 16 + m) * 64 + ks * 32 + g * 8];
            acc2[t] = __builtin_amdgcn_mfma_f32_16x16x32_bf16(afrag, bfrag, acc2[t], 0, 0, 0);
        }
    }

    // ---- epilogue 2a: pv = acc2 + ES(bf16); LN stats via 16-lane shfl reduce ----
    float pv[4][4];            // [t][r]
    float s[4] = {0,0,0,0}, s2[4] = {0,0,0,0};
#pragma unroll
    for (int t = 0; t < 4; ++t) {
#pragma unroll
        for (int r = 0; r < 4; ++r) {
            int rowl = wu * 16 + g * 4 + r;
            float esv = __uint_as_float((unsigned)es[rowl * 68 + t * 16 + m] << 16);
            float v = acc2[t][r] + esv;
            pv[t][r] = v;
            s[r] += v; s2[r] = fmaf(v, v, s2[r]);
        }
    }
#pragma unroll
    for (int o = 1; o < 16; o <<= 1) {
#pragma unroll
        for (int r = 0; r < 4; ++r) {
            s[r]  += __shfl_xor(s[r], o);
            s2[r] += __shfl_xor(s2[r], o);
        }
    }
    float mu[4], rs[4];
#pragma unroll
    for (int r = 0; r < 4; ++r) {
        mu[r] = s[r] * 0.015625f;
        float var = fmaxf(s2[r] * 0.015625f - mu[r] * mu[r], 0.f);
        rs[r] = rsqrtf(var + 1e-5f);
    }
    // ---- epilogue 2b: gelu(LN) -> cvt_pk bf16 into h1b (wave-private WAR; bijective swz) ----
#pragma unroll
    for (int tp = 0; tp < 2; ++tp) {
#pragma unroll
        for (int r = 0; r < 4; ++r) {
            int rowl = wu * 16 + g * 4 + r;
            int c0 = tp * 32 + m, c1 = c0 + 16;
            float l0 = fmaf((pv[tp * 2][r] - mu[r]) * rs[r], prm[64 + c0], prm[128 + c0]);
            float l1 = fmaf((pv[tp * 2 + 1][r] - mu[r]) * rs[r], prm[64 + c1], prm[128 + c1]);
            unsigned pk = cvt_pk_bf16(gelu_fast(l0), gelu_fast(l1));
            int swz = (rowl & 7) << 4;
            *(unsigned short*)((char*)h1b + ((rowl * 128 + c0 * 2) ^ swz)) = (unsigned short)pk;
            *(unsigned short*)((char*)h1b + ((rowl * 128 + c1 * 2) ^ swz)) = (unsigned short)(pk >> 16);
        }
    }
    // ---- GEMM3: bias[16 rows x 16 cols(4 used)] = gelu_ln[16x64] @ ow_pad[64x16] ----
    f32x4 accH = {0,0,0,0};
#pragma unroll
    for (int ks = 0; ks < 2; ++ks) {
        int rowl = wu * 16 + m;
        int byte = (rowl * 128 + ks * 64 + g * 16) ^ ((m & 7) << 4);
        short8 afrag = *(const short8*)((const char*)h1b + byte);
        short8 bfrag = *(const short8*)&owbt[m * 64 + ks * 32 + g * 8];
        accH = __builtin_amdgcn_mfma_f32_16x16x32_bf16(afrag, bfrag, accH, 0, 0, 0);
    }
    // C layout: col = m (head), row = g*4 + r  [m89]; bias_lds rows wave-private
    if (m < 4) {
        float ob = outb[m];
#pragma unroll
        for (int r = 0; r < 4; ++r) {
            int rowl = wu * 16 + g * 4 + r;
            bias_lds[rowl * 9 + m] = accH[r] + ob;
        }
    }
    __syncthreads();   // the ONLY block barrier: bias_lds transposed cross-wave read below
    // ---- final: wave w writes head h=w, coalesced ----
    {
        float pmv = pm[r0 + lane] ? 1.f : 0.f;
        size_t ob = (size_t)(b * 4 + wu) * 1048576u + (size_t)i * 1024u + (size_t)(j0 + lane);
        bias_out[ob] = bias_lds[lane * 9 + wu] * pmv;
    }
}

// ---------------- attention ----------------
__global__ __launch_bounds__(256) void attn_kernel(
        const float* __restrict__ q, const float* __restrict__ kt, const float* __restrict__ v,
        const unsigned char* __restrict__ pm, const unsigned char* __restrict__ vm,
        const float* __restrict__ bias, float* __restrict__ attn, float* __restrict__ ao) {
    __shared__ float pbuf[4][1024];
    int tid = threadIdx.x;
    int w = tid >> 6, lane = tid & 63;
    int blk = blockIdx.x;
    int it = blk & 63;
    int bh = blk >> 6;
    int b = bh >> 2, h = bh & 3;
    int i0 = __builtin_amdgcn_readfirstlane(it * 16 + w * 4);
    const float* __restrict__ qr = q + ((size_t)bh * 1024 + i0) * 64;
    const float4* __restrict__ kt4 = (const float4*)kt;
    const float4* __restrict__ v4 = (const float4*)v;
    const float4* __restrict__ bias4 = (const float4*)bias;
    float4* __restrict__ attn4 = (float4*)attn;
    float4* __restrict__ ao4 = (float4*)ao;

    float4 lg[4][4];
#pragma unroll
    for (int jt = 0; jt < 4; ++jt) {
        float4 a0 = {0,0,0,0}, a1 = a0, a2 = a0, a3 = a0;
#pragma unroll 4
        for (int d = 0; d < 64; ++d) {
            float4 kv = kt4[((size_t)bh * 64 + d) * 256 + jt * 64 + lane];
            a0 = fma4(qr[d], kv, a0);
            a1 = fma4(qr[64 + d], kv, a1);
            a2 = fma4(qr[128 + d], kv, a2);
            a3 = fma4(qr[192 + d], kv, a3);
        }
#pragma unroll
        for (int rr = 0; rr < 4; ++rr) {
            float4 acc = (rr == 0) ? a0 : ((rr == 1) ? a1 : ((rr == 2) ? a2 : a3));
            float4 bv = bias4[((size_t)bh * 1024 + i0 + rr) * 256 + jt * 64 + lane];
            float4 l;
            l.x = fmaf(acc.x, 0.125f, bv.x);
            l.y = fmaf(acc.y, 0.125f, bv.y);
            l.z = fmaf(acc.z, 0.125f, bv.z);
            l.w = fmaf(acc.w, 0.125f, bv.w);
            lg[rr][jt] = l;
        }
    }
#pragma unroll
    for (int rr = 0; rr < 4; ++rr) {
        int i = i0 + rr;
        bool vld = vm[b * 1024 + i] != 0;
        float4 ev[4];
        float pmax = -FLT_MAX;
#pragma unroll
        for (int jt = 0; jt < 4; ++jt) {
            uchar4 m4 = *(const uchar4*)&pm[((size_t)b * 1024 + i) * 1024 + jt * 256 + lane * 4];
            int jb = jt * 256 + lane * 4;
            float4 l = lg[rr][jt];
            l.x = (m4.x || (!vld && (jb + 0) == i)) ? l.x : -FLT_MAX;
            l.y = (m4.y || (!vld && (jb + 1) == i)) ? l.y : -FLT_MAX;
            l.z = (m4.z || (!vld && (jb + 2) == i)) ? l.z : -FLT_MAX;
            l.w = (m4.w || (!vld && (jb + 3) == i)) ? l.w : -FLT_MAX;
            lg[rr][jt] = l;
            pmax = fmaxf(pmax, fmaxf(fmaxf(l.x, l.y), fmaxf(l.z, l.w)));
        }
        pmax = wave_max(pmax);
        float s1sum = 0.f;
#pragma unroll
        for (int jt = 0; jt < 4; ++jt) {
            float4 l = lg[rr][jt];
            float4 e;
            e.x = __expf(l.x - pmax); e.y = __expf(l.y - pmax);
            e.z = __expf(l.z - pmax); e.w = __expf(l.w - pmax);
            ev[jt] = e;
            s1sum += (e.x + e.y) + (e.z + e.w);
        }
        s1sum = wave_sum(s1sum);
        float inv1 = 1.f / s1sum;
        float s2sum = 0.f;
#pragma unroll
        for (int jt = 0; jt < 4; ++jt) {
            uchar4 m4 = *(const uchar4*)&pm[((size_t)b * 1024 + i) * 1024 + jt * 256 + lane * 4];
            float4 e = ev[jt];
            e.x = m4.x ? e.x * inv1 : 0.f;
            e.y = m4.y ? e.y * inv1 : 0.f;
            e.z = m4.z ? e.z * inv1 : 0.f;
            e.w = m4.w ? e.w * inv1 : 0.f;
            ev[jt] = e;
            s2sum += (e.x + e.y) + (e.z + e.w);
        }
        s2sum = wave_sum(s2sum);
        float inv2 = 1.f / fmaxf(s2sum, 1e-6f);
#pragma unroll
        for (int jt = 0; jt < 4; ++jt) {
            float4 e = ev[jt];
            e.x *= inv2; e.y *= inv2; e.z *= inv2; e.w *= inv2;
            attn4[((size_t)bh * 1024 + i) * 256 + jt * 64 + lane] = e;
            *(float4*)&pbuf[w][jt * 256 + lane * 4] = e;
        }
        __syncthreads();
        int dq = lane & 15, grp = lane >> 4;
        float4 o = {0,0,0,0};
#pragma unroll 4
        for (int t = 0; t < 64; ++t) {
            int jj = grp * 4 + t * 16;
            float4 p4 = *(const float4*)&pbuf[w][jj];
            float4 v0 = v4[((size_t)bh * 1024 + jj + 0) * 16 + dq];
            float4 v1 = v4[((size_t)bh * 1024 + jj + 1) * 16 + dq];
            float4 v2 = v4[((size_t)bh * 1024 + jj + 2) * 16 + dq];
            float4 v3 = v4[((size_t)bh * 1024 + jj + 3) * 16 + dq];
            o = fma4(p4.x, v0, o); o = fma4(p4.y, v1, o);
            o = fma4(p4.z, v2, o); o = fma4(p4.w, v3, o);
        }
        o.x += __shfl_xor(o.x, 16); o.y += __shfl_xor(o.y, 16);
        o.z += __shfl_xor(o.z, 16); o.w += __shfl_xor(o.w, 16);
        o.x += __shfl_xor(o.x, 32); o.y += __shfl_xor(o.y, 32);
        o.z += __shfl_xor(o.z, 32); o.w += __shfl_xor(o.w, 32);
        if (grp == 0) ao4[((size_t)(b * 1024 + i) * 4 + h) * 16 + dq] = o;
        __syncthreads();
    }
}

// ---------------- output projection ----------------
__global__ __launch_bounds__(256) void outproj_kernel(
        const float* __restrict__ ao, const float* __restrict__ Wo,
        const float* __restrict__ bo, float* __restrict__ out) {
    __shared__ float As[32][68];
    __shared__ float Bs[32][68];
    int tid = threadIdx.x;
    int bx = blockIdx.x, by = blockIdx.y;
    int col0 = bx * 64, row0 = by * 64;
    int tx = tid & 15, ty = tid >> 4;
    int lm = tid >> 3, lk = (tid & 7) * 4;
    int bn = (tid & 15) * 4, bk = tid >> 4;
    float4 acc0 = {0,0,0,0}, acc1 = acc0, acc2 = acc0, acc3 = acc0;
    for (int k0 = 0; k0 < 256; k0 += 32) {
        float4 a0 = *(const float4*)&ao[(size_t)(row0 + lm) * 256 + k0 + lk];
        float4 a1 = *(const float4*)&ao[(size_t)(row0 + lm + 32) * 256 + k0 + lk];
        float4 b0 = *(const float4*)&Wo[(size_t)(k0 + bk) * 512 + col0 + bn];
        float4 b1 = *(const float4*)&Wo[(size_t)(k0 + bk + 16) * 512 + col0 + bn];
        __syncthreads();
        As[lk + 0][lm] = a0.x; As[lk + 1][lm] = a0.y; As[lk + 2][lm] = a0.z; As[lk + 3][lm] = a0.w;
        As[lk + 0][lm + 32] = a1.x; As[lk + 1][lm + 32] = a1.y; As[lk + 2][lm + 32] = a1.z; As[lk + 3][lm + 32] = a1.w;
        *(float4*)&Bs[bk][bn] = b0;
        *(float4*)&Bs[bk + 16][bn] = b1;
        __syncthreads();
#pragma unroll
        for (int kk = 0; kk < 32; ++kk) {
            float4 av = *(const float4*)&As[kk][ty * 4];
            float4 bv = *(const float4*)&Bs[kk][tx * 4];
            acc0 = fma4(av.x, bv, acc0);
            acc1 = fma4(av.y, bv, acc1);
            acc2 = fma4(av.z, bv, acc2);
            acc3 = fma4(av.w, bv, acc3);
        }
    }
#pragma unroll
    for (int r = 0; r < 4; ++r) {
        float4 a = (r == 0) ? acc0 : ((r == 1) ? acc1 : ((r == 2) ? acc2 : acc3));
        int gr = row0 + ty * 4 + r;
        float vals[4] = {a.x, a.y, a.z, a.w};
#pragma unroll
        for (int c = 0; c < 4; ++c) {
            int gc = col0 + tx * 4 + c;
            out[(size_t)gr * 512 + gc] = vals[c] + bo[gc];
        }
    }
}

extern "C" void kernel_launch(void* const* d_in, const int* in_sizes, int n_in,
                              void* d_out, int out_size, void* d_ws, size_t ws_size,
                              hipStream_t stream) {
    (void)in_sizes; (void)n_in; (void)out_size; (void)ws_size;
    const float* x    = (const float*)d_in[0];
    const void*  pmr  = d_in[1];
    const void*  vmr  = d_in[2];
    const float* cf   = (const float*)d_in[3];
    const int* dist_b = (const int*)d_in[4];
    const int* dir_b  = (const int*)d_in[5];
    const int* role_b = (const int*)d_in[6];
    const int* hop_b  = (const int*)d_in[7];
    const int* edge_b = (const int*)d_in[8];
    const int* sp_b   = (const int*)d_in[9];
    const int* same_b = (const int*)d_in[10];
    const int* deg_ids = (const int*)d_in[11];
    const int* ct_ids  = (const int*)d_in[12];
    const float* Wq = (const float*)d_in[13];
    const float* Wk = (const float*)d_in[14];
    const float* Wv = (const float*)d_in[15];
    const float* Wo = (const float*)d_in[16];
    const float* bo = (const float*)d_in[17];
    const float* w1 = (const float*)d_in[18];
    const float* b1 = (const float*)d_in[19];
    const float* w2 = (const float*)d_in[20];
    const float* b2 = (const float*)d_in[21];
    const float* e_dist = (const float*)d_in[22];
    const float* e_dir  = (const float*)d_in[23];
    const float* e_role = (const float*)d_in[24];
    const float* e_hop  = (const float*)d_in[25];
    const float* e_edge = (const float*)d_in[26];
    const float* e_sp   = (const float*)d_in[27];
    const float* e_deg  = (const float*)d_in[28];
    const float* e_ct   = (const float*)d_in[29];
    const float* e_same = (const float*)d_in[30];
    const float* lng  = (const float*)d_in[31];
    const float* lnb  = (const float*)d_in[32];
    const float* ow   = (const float*)d_in[33];
    const float* outb = (const float*)d_in[34];

    char* ws = (char*)d_ws;
    unsigned char* pm8 = (unsigned char*)(ws + WS_PM);
    unsigned char* vm8 = (unsigned char*)(ws + WS_VM);
    unsigned short* w1tb = (unsigned short*)(ws + WS_W1TB);
    unsigned short* w2tb = (unsigned short*)(ws + WS_W2TB);
    unsigned short* owbt = (unsigned short*)(ws + WS_OWBT);
    float* q   = (float*)(ws + WS_Q);
    float* kt  = (float*)(ws + WS_KT);
    float* v   = (float*)(ws + WS_V);
    float* ao  = (float*)(ws + WS_AO);

    float* out  = (float*)d_out;
    float* attn = out + 1048576;     // [2,4,1024,1024]
    float* bias = out + 9437184;     // [2,4,1024,1024]

    hipLaunchKernelGGL(prep_kernel, dim3(1), dim3(256), 0, stream, w1, w2, ow, w1tb, w2tb, owbt);
    hipLaunchKernelGGL(mask_kernel, dim3(2048), dim3(256), 0, stream, pmr, vmr, pm8, vm8);
    hipLaunchKernelGGL(qkv_kernel, dim3(12, 32), dim3(256), 0, stream, x, Wq, Wk, Wv, q, kt, v);
    hipLaunchKernelGGL(pair_kernel, dim3(32768), dim3(256), 0, stream,
                       cf, dist_b, dir_b, role_b, hop_b, edge_b, sp_b, same_b, deg_ids, ct_ids,
                       e_dist, e_dir, e_role, e_hop, e_edge, e_sp, e_same, e_deg, e_ct,
                       b1, b2, w1tb, w2tb, owbt, lng, lnb, outb, pm8, bias);
    hipLaunchKernelGGL(attn_kernel, dim3(512), dim3(256), 0, stream,
                       q, kt, v, pm8, vm8, bias, attn, ao);
    hipLaunchKernelGGL(outproj_kernel, dim3(8, 32), dim3(256), 0, stream, ao, Wo, bo, out);
}